// Round 4
// baseline (313.081 us; speedup 1.0000x reference)
//
#include <hip/hip_runtime.h>
#include <hip/hip_bf16.h>

// GraphConvolution: out = relu( (W@x + b) @ adj^T + x ), B=4096, C=256, N=25.
// R9: single-barrier phase, zero x-staging. Lessons applied:
//  - R8 lesson: direct strided stores cause RFO (+105MB fetch) -> keep the
//    wave-private outS LDS transpose + full-line dwordx4 stores (R7 pattern).
//  - x is LLC-resident (FETCH 56MB < |x|) and a block tile is 25.6KB (L1-fit):
//    read x straight from global (agg frags = 32B/lane gathers; residual =
//    16 scalar L1/L2 hits). xs LDS + DMA + vmcnt machinery deleted.
//  - ys double-buffered (26.4KB) + outS separate & wave-private (25.6KB):
//    ONE lgkmcnt(0)+s_barrier per iteration. LDS 52KB -> 2 blocks/CU,
//    16 waves/CU. bias in 8 pinned regs (no biasS).
// Phase bi: {gather x[bi+1] regs | gemm(bi) reads ys[p] | epilogue residual
//            from global | outS stage | coalesced stores | agg(bi+1)->ys[p^1]}

#define BATCH 4096
#define C 256
#define N 25
#define NB 8
#define XW 6400          // floats per batch tile (256*25)
#define YSTR 264         // ys bf16 row stride (528 B, 16B-aligned rows)
#define YROWS 25
#define YBUF (YROWS * YSTR)   // 6600 bf16 = 13200 B per buffer

typedef __bf16 bf16x8 __attribute__((ext_vector_type(8)));
typedef float f32x4 __attribute__((ext_vector_type(4)));

// ---- prep: Wshuf[(T*8+kk)*64+lane] = MFMA A-fragment, o-tile T (o=T*16+l15) ----
__global__ void prep_kernel(const float* __restrict__ W, const float* __restrict__ adj,
                            bf16x8* __restrict__ Wshuf, float* __restrict__ adjS) {
    int i = blockIdx.x * 256 + threadIdx.x;       // 8192 = 128 frags x 64 lanes
    int f = i >> 6, l = i & 63;
    int T = f >> 3, kk = f & 7;
    int quad = l >> 4, l15 = l & 15;
    int o = T * 16 + l15;
    int cb = kk * 32 + quad * 8;
    bf16x8 v;
    #pragma unroll
    for (int j = 0; j < 8; ++j) v[j] = (__bf16)W[o * C + cb + j];
    Wshuf[i] = v;
    if (blockIdx.x == 0 && threadIdx.x < 32) {
        float s = 0.f;
        if (threadIdx.x < N)
            for (int n = 0; n < N; ++n) s += adj[threadIdx.x * N + n];
        adjS[threadIdx.x] = s;
    }
}

__global__ __launch_bounds__(512, 4) void gcn_kernel(
    const float* __restrict__ x, const float* __restrict__ adj,
    const float* __restrict__ bias, const float* __restrict__ adjSg,
    const bf16x8* __restrict__ Wshuf, float* __restrict__ out)
{
    __shared__ __align__(16) __bf16 ys2[2][YBUF];   // 26400 B, y double-buffer
    __shared__ __align__(16) float  outS[XW];       // 25600 B, wave-private slices
    __bf16* const adjbf = (__bf16*)outS;            // alias: init-only, 2560 B
                                                    // total LDS = 52000 B

    const int tid = threadIdx.x;                   // 0..511
    const int wv = tid >> 6, lane = tid & 63;      // 8 waves
    const int quad = lane >> 4, l15 = lane & 15;
    const int o0 = wv * 32;                        // wave's o-range == c-range
    const int b0 = blockIdx.x * NB;

    // ---- one-time: adj into aliased LDS, pinned W fragments, bias in regs ----
    for (int e = tid; e < 32 * 32; e += 512) {
        int m = e >> 5, n = e & 31;
        adjbf[m * 40 + n] = (m < N && n < N) ? (__bf16)adj[m * N + n] : (__bf16)0.f;
    }

    bf16x8 af[8][2];   // 64 regs, coalesced 1KB loads
    #pragma unroll
    for (int kk = 0; kk < 8; ++kk)
        #pragma unroll
        for (int ot = 0; ot < 2; ++ot)
            af[kk][ot] = Wshuf[(((wv * 2 + ot) * 8 + kk) << 6) + lane];

    float biasR[8];    // bias for the wave's 8 o-rows (i = ot*4 + r2)
    #pragma unroll
    for (int i = 0; i < 8; ++i)
        biasR[i] = bias[o0 + (i >> 2) * 16 + quad * 4 + (i & 3)];

    const float aS0 = adjSg[l15];
    const float aS1 = adjSg[16 + l15];

    __syncthreads();   // adjbf visible
    const bf16x8 a0 = *(const bf16x8*)&adjbf[l15 * 40 + quad * 8];
    const bf16x8 a1 = *(const bf16x8*)&adjbf[(16 + l15) * 40 + quad * 8];
    asm volatile("s_waitcnt lgkmcnt(0)" ::: "memory");
    __builtin_amdgcn_s_barrier();   // all adjbf reads done before outS reuse

    // gather the wave's x fragment rows (32B/lane contiguous; L1/L2/LLC-hit)
    auto aggLoad = [&](const float* xb, float xv[2][8]) {
        #pragma unroll
        for (int ctl = 0; ctl < 2; ++ctl) {
            const int c = o0 + ctl * 16 + l15;
            if (quad < 3) {
                #pragma unroll
                for (int j = 0; j < 8; ++j) xv[ctl][j] = xb[c * N + quad * 8 + j];
            } else {
                xv[ctl][0] = xb[c * N + 24];   // n=24 only; rest zero-filled later
            }
        }
    };
    // agg: y[m][c] = sum_n adj[m][n] * x[c][n] for the wave's 32 c-rows
    auto aggCompute = [&](const float xv[2][8], __bf16* ysw) {
        #pragma unroll
        for (int ctl = 0; ctl < 2; ++ctl) {
            const int c = o0 + ctl * 16 + l15;
            bf16x8 xf;
            if (quad < 3) {
                #pragma unroll
                for (int j = 0; j < 8; ++j) xf[j] = (__bf16)xv[ctl][j];
            } else {
                xf[0] = (__bf16)xv[ctl][0];
                #pragma unroll
                for (int j = 1; j < 8; ++j) xf[j] = (__bf16)0.f;
            }
            f32x4 y0 = __builtin_amdgcn_mfma_f32_16x16x32_bf16(a0, xf, (f32x4)0.f, 0, 0, 0);
            f32x4 y1 = __builtin_amdgcn_mfma_f32_16x16x32_bf16(a1, xf, (f32x4)0.f, 0, 0, 0);
            #pragma unroll
            for (int r2 = 0; r2 < 4; ++r2) {
                ysw[(quad * 4 + r2) * YSTR + c] = (__bf16)y0[r2];
                if (quad * 4 + r2 < 9)   // rows 16..24 only (25 rows total)
                    ysw[(16 + quad * 4 + r2) * YSTR + c] = (__bf16)y1[r2];
            }
        }
    };

    // ---- prologue: agg for batch 0 into ys2[0] ----
    {
        float xv[2][8];
        aggLoad(x + (size_t)b0 * XW, xv);
        aggCompute(xv, ys2[0]);
    }
    asm volatile("s_waitcnt lgkmcnt(0)" ::: "memory");
    __builtin_amdgcn_s_barrier();

    const int row1 = (l15 < 9) ? (16 + l15) : 24;  // clamped ys row (cols discarded)

    #pragma unroll 1
    for (int bi = 0; bi < NB; ++bi) {
        const int p = bi & 1;
        const __bf16* ysr = ys2[p];
        const float* xb = x + (size_t)(b0 + bi) * XW;
        float* outb = out + (size_t)(b0 + bi) * XW;
        const bool pf = (bi + 1 < NB);

        // ---- 1) issue next-batch x gathers early (land under the GEMM) ----
        float xv[2][8];
        if (pf) aggLoad(x + (size_t)(b0 + bi + 1) * XW, xv);

        // ---- 2) main GEMM: out[o][m] += W[o][c]*y[c][m]; af pinned ----
        f32x4 acc[2][2];
        #pragma unroll
        for (int ot = 0; ot < 2; ++ot) { acc[ot][0] = (f32x4)0.f; acc[ot][1] = (f32x4)0.f; }
        #pragma unroll
        for (int kk = 0; kk < 8; ++kk) {
            bf16x8 bfr0 = *(const bf16x8*)&ysr[l15  * YSTR + kk * 32 + quad * 8];
            bf16x8 bfr1 = *(const bf16x8*)&ysr[row1 * YSTR + kk * 32 + quad * 8];
            #pragma unroll
            for (int ot = 0; ot < 2; ++ot) {
                acc[ot][0] = __builtin_amdgcn_mfma_f32_16x16x32_bf16(af[kk][ot], bfr0, acc[ot][0], 0, 0, 0);
                acc[ot][1] = __builtin_amdgcn_mfma_f32_16x16x32_bf16(af[kk][ot], bfr1, acc[ot][1], 0, 0, 0);
            }
        }

        // ---- 3) epilogue: residual straight from global (L1/L2 hit), stage outS ----
        #pragma unroll
        for (int ot = 0; ot < 2; ++ot)
            #pragma unroll
            for (int r2 = 0; r2 < 4; ++r2) {
                const int o = o0 + ot * 16 + quad * 4 + r2;
                const float bia = biasR[ot * 4 + r2];
                float v0 = acc[ot][0][r2] + bia * aS0 + xb[o * N + l15];
                outS[o * N + l15] = v0 > 0.f ? v0 : 0.f;
                if (l15 < 9) {
                    float v1 = acc[ot][1][r2] + bia * aS1 + xb[o * N + 16 + l15];
                    outS[o * N + 16 + l15] = v1 > 0.f ? v1 : 0.f;
                }
            }

        // ---- 4) coalesced full-line stores of own slice (wave-private) ----
        #pragma unroll
        for (int rr = 0; rr < 4; ++rr)
            if (rr < 3 || lane < 8) {
                int i4 = wv * 200 + rr * 64 + lane;
                ((float4*)outb)[i4] = ((const float4*)outS)[i4];
            }

        // ---- 5) agg for bi+1 into the other ys buffer ----
        if (pf) aggCompute(xv, ys2[p ^ 1]);

        // single phase barrier: ys[p^1] visible; all ys[p]/outS LDS ops drained.
        asm volatile("s_waitcnt lgkmcnt(0)" ::: "memory");
        __builtin_amdgcn_s_barrier();
    }
}

extern "C" void kernel_launch(void* const* d_in, const int* in_sizes, int n_in,
                              void* d_out, int out_size, void* d_ws, size_t ws_size,
                              hipStream_t stream) {
    (void)in_sizes; (void)n_in; (void)out_size; (void)ws_size;
    const float* x    = (const float*)d_in[0];   // [4096, 256, 25]
    const float* adj  = (const float*)d_in[1];   // [25, 25]
    const float* W    = (const float*)d_in[2];   // [256, 256]
    const float* bias = (const float*)d_in[3];   // [256]
    float* out = (float*)d_out;

    unsigned char* ws = (unsigned char*)d_ws;
    bf16x8* Wshuf = (bf16x8*)ws;                 // 131072 B
    float*  adjS  = (float*)(ws + 131072);       // 128 B

    prep_kernel<<<32, 256, 0, stream>>>(W, adj, Wshuf, adjS);
    gcn_kernel<<<BATCH / NB, 512, 0, stream>>>(x, adj, bias, adjS, Wshuf, out);
}

// Round 6
// 230.734 us; speedup vs baseline: 1.3569x; 1.3569x over previous
//
#include <hip/hip_runtime.h>
#include <hip/hip_bf16.h>

// GraphConvolution: out = relu( (W@x + b) @ adj^T + x ), B=4096, C=256, N=25.
// R11 = R10 resubmit (container-level infra failure, no kernel signal) with
// one hardening tweak: xsT rows 25..31 zeroed at init so the discarded MFMA
// columns read deterministic zeros instead of uninitialized LDS.
//
// R10 design: re-associated single-barrier pipeline.
//   out = (W@x + b)@adjT + x  ==  s=W@x first (contract c, block-shared xsT),
//   then out = s@adjT (contract n=25, WAVE-LOCAL) -> the ys cross-wave handoff
//   and 2 of 3 barriers disappear.
//  - xsT[n][c] bf16, double-buffered (33.8KB): staged pre-transposed via short
//    reg window (16 regs, not held across MFMA -> no R6/R9 spill). GEMM1
//    B-frags = clean ds_read_b128.
//  - s -> A-frag transpose through WAVE-PRIVATE ss (aliases outS slice): no
//    barrier; same-wave LDS ordering via data deps + compiler lgkmcnt.
//  - bias as pseudo-channel n=25: ss[o][25]=b[o], adjT[25][m]=aS[m] -> bias*aS
//    computed inside MFMA2. ss cols >=25 zeroed.
//  - residual+relu at store time from GLOBAL f32x4 (coalesced, L2-hit).
//  - 32x32x16 MFMA: af 16 frags (64 regs); acc f32x16 reused for both GEMMs.
//  - ONE asm barrier per phase (lgkmcnt only, no vmcnt drain anywhere).
// LDS: xsT2 33792 + outS 25600 + adjTf 2048 = 61440 B -> 2 blocks/CU.

#define BATCH 4096
#define C 256
#define N 25
#define NB 8
#define XW 6400          // floats per batch tile (256*25)
#define CSTRT 264        // xsT row stride in bf16 (528 B, 16B-mult)
#define SSTR 40          // ss row stride in bf16 (80 B, 16B-mult)

typedef __bf16 bf16x8 __attribute__((ext_vector_type(8)));
typedef float f32x16 __attribute__((ext_vector_type(16)));

// ---- prep: Wshuf[(wv*16+kt)*64+l] = 32x32x16 A-frag of W for wave wv ----
// lane l holds A[row = wv*32 + (l&31)][k = kt*16 + (l>>5)*8 + j], j=0..7
__global__ void prep_kernel(const float* __restrict__ W, const float* __restrict__ adj,
                            bf16x8* __restrict__ Wshuf, float* __restrict__ adjS) {
    int i = blockIdx.x * 256 + threadIdx.x;       // 8192 = 128 frags x 64 lanes
    int f = i >> 6, l = i & 63;
    int wvp = f >> 4, kt = f & 15;
    int row = wvp * 32 + (l & 31);
    int cb  = kt * 16 + ((l >> 5) << 3);
    bf16x8 v;
    #pragma unroll
    for (int j = 0; j < 8; ++j) v[j] = (__bf16)W[row * C + cb + j];
    Wshuf[i] = v;
    if (blockIdx.x == 0 && threadIdx.x < 32) {
        float s = 0.f;
        if (threadIdx.x < N)
            for (int n = 0; n < N; ++n) s += adj[threadIdx.x * N + n];
        adjS[threadIdx.x] = s;
    }
}

__global__ __launch_bounds__(512, 4) void gcn_kernel(
    const float* __restrict__ x, const float* __restrict__ adj,
    const float* __restrict__ bias, const float* __restrict__ adjSg,
    const bf16x8* __restrict__ Wshuf, float* __restrict__ out)
{
    __shared__ __align__(16) __bf16 xsT[2][32 * CSTRT]; // 33792 B, x^T bf16 dbuf
    __shared__ __align__(16) float  outS[XW];           // 25600 B; ss aliases slices
    __shared__ __align__(16) __bf16 adjTf[2 * 64 * 8];  //  2048 B, adjT B-frags

    const int tid = threadIdx.x;                   // 0..511
    const int wv = tid >> 6, lane = tid & 63;      // 8 waves
    const int l31 = lane & 31, lh = lane >> 5;
    const int o0 = wv * 32;                        // wave's 32 output rows
    const int b0 = blockIdx.x * NB;

    // wave-private s scratch: 32 rows x SSTR bf16 = 2560 B inside own outS slice
    __bf16* const ssw = (__bf16*)((char*)outS + wv * 3200);

    // ---- one-time init ----
    // zero xsT rows N..31 (both buffers): deterministic zeros for discarded cols
    for (int e = tid; e < 2 * (32 - N) * CSTRT; e += 512) {
        int buf = e / ((32 - N) * CSTRT), r = e % ((32 - N) * CSTRT);
        xsT[buf][(N + r / CSTRT) * CSTRT + (r % CSTRT)] = (__bf16)0.f;
    }
    // adjT B-frags: lane l holds B[n = kt*16+(l>>5)*8+j][m = l&31];
    // n<25 -> adj[m][n]; n==25 -> aS[m] (bias channel); else 0. m>=25 -> 0.
    if (tid < 128) {
        int kt = tid >> 6, l = tid & 63;
        int m = l & 31, nb = kt * 16 + ((l >> 5) << 3);
        bf16x8 v;
        #pragma unroll
        for (int j = 0; j < 8; ++j) {
            int n = nb + j;
            float val = 0.f;
            if (m < N) { if (n < N) val = adj[m * N + n]; else if (n == N) val = adjSg[m]; }
            v[j] = (__bf16)val;
        }
        *(bf16x8*)&adjTf[(kt * 64 + l) * 8] = v;
    }

    bf16x8 af[16];   // 64 regs: W A-frags, coalesced 1KB loads
    #pragma unroll
    for (int kt = 0; kt < 16; ++kt)
        af[kt] = Wshuf[(wv * 16 + kt) * 64 + lane];

    const float biasL = bias[o0 + l31];   // used by lanes<32 for ss bias column

    // ---- prologue: stage x[b0] transposed into xsT[0] ----
    {
        const float4* xb4 = (const float4*)(x + (size_t)b0 * XW);
        #pragma unroll
        for (int q = 0; q < 4; ++q)
            if (q < 3 || lane < 8) {
                int i4 = wv * 200 + q * 64 + lane;
                float4 v = xb4[i4];
                int e = i4 * 4;
                int c = e / N, n = e - c * N;
                float fv[4] = {v.x, v.y, v.z, v.w};
                #pragma unroll
                for (int j = 0; j < 4; ++j) {
                    xsT[0][n * CSTRT + c] = (__bf16)fv[j];
                    ++n; if (n == N) { n = 0; ++c; }
                }
            }
    }
    __syncthreads();   // adjTf + xsT[0] + zero-rows visible (full drain, once)

    #pragma unroll 1
    for (int bi = 0; bi < NB; ++bi) {
        const int p = bi & 1;
        const __bf16* xr = xsT[p];
        const float* xb = x + (size_t)(b0 + bi) * XW;
        float* outb = out + (size_t)(b0 + bi) * XW;
        const bool pf = (bi + 1 < NB);

        // ---- A) stage loads for x[bi+1] (short reg window; writes after GEMM1)
        float4 sv[4];
        if (pf) {
            const float4* xn4 = (const float4*)(x + (size_t)(b0 + bi + 1) * XW);
            #pragma unroll
            for (int q = 0; q < 4; ++q)
                if (q < 3 || lane < 8) sv[q] = xn4[wv * 200 + q * 64 + lane];
        }

        // ---- B) GEMM1: s[o][n] = sum_c W[o][c] x[c][n], 16 MFMA 32x32x16 ----
        f32x16 acc = (f32x16)0.f;
        #pragma unroll
        for (int kt = 0; kt < 16; ++kt) {
            bf16x8 xf = *(const bf16x8*)&xr[l31 * CSTRT + kt * 16 + lh * 8];
            acc = __builtin_amdgcn_mfma_f32_32x32x16_bf16(af[kt], xf, acc, 0, 0, 0);
        }

        // ---- C) s -> wave-private ss (cols >=25 zeroed; bias col rewritten) ----
        #pragma unroll
        for (int r = 0; r < 16; ++r) {
            int o = (r & 3) + 8 * (r >> 2) + 4 * lh;
            ssw[o * SSTR + l31] = (__bf16)((l31 < N) ? acc[r] : 0.f);
        }
        if (lane < 32) ssw[lane * SSTR + N] = (__bf16)biasL;   // n=25 = bias channel

        // ---- D) MFMA2: out[o][m] = sum_n s[o][n] adjT[n][m]  (n wave-local) ----
        acc = (f32x16)0.f;   // reuse same registers (unified-file budget)
        #pragma unroll
        for (int kt = 0; kt < 2; ++kt) {
            bf16x8 sA = *(const bf16x8*)&ssw[l31 * SSTR + kt * 16 + lh * 8];
            bf16x8 aB = *(const bf16x8*)&adjTf[(kt * 64 + lane) * 8];
            acc = __builtin_amdgcn_mfma_f32_32x32x16_bf16(sA, aB, acc, 0, 0, 0);
        }

        // ---- E) stage outS (wave-private slice; includes bias*aS via MFMA) ----
        #pragma unroll
        for (int r = 0; r < 16; ++r) {
            int o = (r & 3) + 8 * (r >> 2) + 4 * lh;
            if (l31 < N) outS[(o0 + o) * N + l31] = acc[r];
        }

        // ---- F) write staged x[bi+1] transposed into xsT[p^1] ----
        if (pf) {
            #pragma unroll
            for (int q = 0; q < 4; ++q)
                if (q < 3 || lane < 8) {
                    int e = (wv * 200 + q * 64 + lane) * 4;
                    int c = e / N, n = e - c * N;
                    float fv[4] = {sv[q].x, sv[q].y, sv[q].z, sv[q].w};
                    #pragma unroll
                    for (int j = 0; j < 4; ++j) {
                        xsT[p ^ 1][n * CSTRT + c] = (__bf16)fv[j];
                        ++n; if (n == N) { n = 0; ++c; }
                    }
                }
        }

        // ---- G) stores: relu(outS + x) with coalesced f32x4 global residual ----
        #pragma unroll
        for (int q = 0; q < 4; ++q)
            if (q < 3 || lane < 8) {
                int i4 = wv * 200 + q * 64 + lane;
                float4 oS = ((const float4*)outS)[i4];
                float4 xg = ((const float4*)xb)[i4];
                float4 r;
                r.x = oS.x + xg.x; r.y = oS.y + xg.y;
                r.z = oS.z + xg.z; r.w = oS.w + xg.w;
                r.x = r.x > 0.f ? r.x : 0.f;  r.y = r.y > 0.f ? r.y : 0.f;
                r.z = r.z > 0.f ? r.z : 0.f;  r.w = r.w > 0.f ? r.w : 0.f;
                ((float4*)outb)[i4] = r;
            }

        // ---- H) single phase barrier: xsT[p^1] visible; xsT[p] reads drained.
        //      LDS drain only -- stores stay in flight (no vmcnt).
        asm volatile("s_waitcnt lgkmcnt(0)\n\ts_barrier" ::: "memory");
    }
}

extern "C" void kernel_launch(void* const* d_in, const int* in_sizes, int n_in,
                              void* d_out, int out_size, void* d_ws, size_t ws_size,
                              hipStream_t stream) {
    (void)in_sizes; (void)n_in; (void)out_size; (void)ws_size;
    const float* x    = (const float*)d_in[0];   // [4096, 256, 25]
    const float* adj  = (const float*)d_in[1];   // [25, 25]
    const float* W    = (const float*)d_in[2];   // [256, 256]
    const float* bias = (const float*)d_in[3];   // [256]
    float* out = (float*)d_out;

    unsigned char* ws = (unsigned char*)d_ws;
    bf16x8* Wshuf = (bf16x8*)ws;                 // 131072 B
    float*  adjS  = (float*)(ws + 131072);       // 128 B

    prep_kernel<<<32, 256, 0, stream>>>(W, adj, Wshuf, adjS);
    gcn_kernel<<<BATCH / NB, 512, 0, stream>>>(x, adj, bias, adjS, Wshuf, out);
}